// Round 12
// baseline (8079.657 us; speedup 1.0000x reference)
//
#include <hip/hip_runtime.h>
#include <hip/hip_bf16.h>

typedef __attribute__((ext_vector_type(8))) short s16x8;
typedef __attribute__((ext_vector_type(4))) float f32x4;

__device__ inline unsigned short f2bf(float f) {
  unsigned u = __builtin_bit_cast(unsigned, f);
  unsigned r = (u + 0x7FFFu + ((u >> 16) & 1u)) >> 16;  // RTNE
  return (unsigned short)r;
}
__device__ inline float bf2f(short v) {
  return __builtin_bit_cast(float, ((unsigned)(unsigned short)v) << 16);
}
__device__ inline float bflo(unsigned w) { return __builtin_bit_cast(float, w << 16); }
__device__ inline float bfhi(unsigned w) { return __builtin_bit_cast(float, w & 0xFFFF0000u); }
__device__ inline float sigf(float x) { return 1.f / (1.f + __expf(-x)); }
__device__ inline float tanhf_(float x) { float e = __expf(2.f * x); return 1.f - 2.f / (e + 1.f); }

// ---------------------------------------------------------------- packers
// gate-interleaved uint4 rows (rows==512): thread j covers src row (j&3)*128+(j>>2);
// dst[m*512+j] = 8 bf16 of cols 8m..8m+7 packed as 4 u32 pairs.
__global__ void packTg4(const float* __restrict__ src, uint4* __restrict__ dst,
                        int scols, int mcnt) {
  int i = blockIdx.x * 256 + threadIdx.x;
  if (i >= mcnt * 512) return;
  int m = i / 512, j = i % 512;
  int row = (j & 3) * 128 + (j >> 2);
  unsigned p[4];
#pragma unroll
  for (int e = 0; e < 4; ++e) {
    int k0 = 8 * m + 2 * e, k1 = k0 + 1;
    float lo = (k0 < scols) ? src[(size_t)row * scols + k0] : 0.f;
    float hi = (k1 < scols) ? src[(size_t)row * scols + k1] : 0.f;
    p[e] = (unsigned)f2bf(lo) | ((unsigned)f2bf(hi) << 16);
  }
  dst[i] = make_uint4(p[0], p[1], p[2], p[3]);
}
// 128x128 weight -> uint4 [16][128]; dst[m2*128+o] covers k = (m2>>2)*32 + (m2&3)*8 .. +7
__global__ void packT4(const float* __restrict__ src, uint4* __restrict__ dst) {
  int i = blockIdx.x * 256 + threadIdx.x;
  if (i >= 16 * 128) return;
  int m2 = i / 128, o = i % 128;
  int k0 = (m2 >> 2) * 32 + (m2 & 3) * 8;
  unsigned p[4];
#pragma unroll
  for (int e = 0; e < 4; ++e) {
    float lo = src[(size_t)o * 128 + k0 + 2 * e];
    float hi = src[(size_t)o * 128 + k0 + 2 * e + 1];
    p[e] = (unsigned)f2bf(lo) | ((unsigned)f2bf(hi) << 16);
  }
  dst[i] = make_uint4(p[0], p[1], p[2], p[3]);
}
// V [t][b][d] bf16 -> vP4[(b*64 + t8)*128 + d] = 8 t's (pairs) for fixed (b,d)
__global__ void vpack4(const unsigned short* __restrict__ vbuf, uint4* __restrict__ dst) {
  int i = blockIdx.x * 256 + threadIdx.x;
  if (i >= 128 * 64 * 128) return;
  int b = i >> 13, t8 = (i >> 7) & 63, d = i & 127;
  const unsigned short* vp = vbuf + (size_t)(8 * t8) * 16384 + (size_t)b * 128 + d;
  unsigned p[4];
#pragma unroll
  for (int e = 0; e < 4; ++e) {
    unsigned lo = vp[(size_t)(2 * e) * 16384];
    unsigned hi = vp[(size_t)(2 * e + 1) * 16384];
    p[e] = lo | (hi << 16);
  }
  dst[i] = make_uint4(p[0], p[1], p[2], p[3]);
}
// bulk f32 -> bf16
__global__ void f2bf_vec(const float* __restrict__ src, unsigned short* __restrict__ dst) {
  size_t i = ((size_t)blockIdx.x * 256 + threadIdx.x) * 4;
  float4 v = *(const float4*)(src + i);
  ushort4 o;
  o.x = f2bf(v.x); o.y = f2bf(v.y); o.z = f2bf(v.z); o.w = f2bf(v.w);
  *(ushort4*)(dst + i) = o;
}

// ---------------------------------------------------------------- GEMM C = A @ B^T + bias
#define BM 128
#define BN 128
#define BKK 32

template<int A_BF16, int C_BF16>
__global__ __launch_bounds__(256) void gemm_bt(const void* __restrict__ Av,
    const float* __restrict__ B, const float* __restrict__ bias,
    void* __restrict__ Cv, int M, int N, int K) {
  __shared__ short sA[BM * BKK];
  __shared__ short sB[BN * BKK];
  const int tid = threadIdx.x;
  const int l = tid & 63;
  const int wid = tid >> 6;
  const int wr = wid >> 1, wc = wid & 1;
  const int lr = l & 15, kg = l >> 4;
  const int bn = blockIdx.x, bm = blockIdx.y;
  const int arow = tid >> 1;
  const int acol = (tid & 1) * 16;

  f32x4 acc[4][4];
#pragma unroll
  for (int i = 0; i < 4; ++i)
#pragma unroll
    for (int j = 0; j < 4; ++j) acc[i][j] = (f32x4){0.f, 0.f, 0.f, 0.f};

  for (int kt = 0; kt < K; kt += BKK) {
    __syncthreads();
    if (A_BF16) {
      const unsigned short* src = (const unsigned short*)Av + (size_t)(bm * BM + arow) * K + kt + acol;
      *(s16x8*)&sA[arow * BKK + acol] = *(const s16x8*)src;
      *(s16x8*)&sA[arow * BKK + acol + 8] = *(const s16x8*)(src + 8);
    } else {
      const float* src = (const float*)Av + (size_t)(bm * BM + arow) * K + kt + acol;
      s16x8 v0, v1;
#pragma unroll
      for (int e = 0; e < 8; ++e) { v0[e] = (short)f2bf(src[e]); v1[e] = (short)f2bf(src[8 + e]); }
      *(s16x8*)&sA[arow * BKK + acol] = v0;
      *(s16x8*)&sA[arow * BKK + acol + 8] = v1;
    }
    {
      const float* src = B + (size_t)(bn * BN + arow) * K + kt + acol;
      s16x8 v0, v1;
#pragma unroll
      for (int e = 0; e < 8; ++e) { v0[e] = (short)f2bf(src[e]); v1[e] = (short)f2bf(src[8 + e]); }
      *(s16x8*)&sB[arow * BKK + acol] = v0;
      *(s16x8*)&sB[arow * BKK + acol + 8] = v1;
    }
    __syncthreads();
    s16x8 af[4], bfr[4];
#pragma unroll
    for (int mi = 0; mi < 4; ++mi)
      af[mi] = *(const s16x8*)&sA[(wr * 64 + mi * 16 + lr) * BKK + kg * 8];
#pragma unroll
    for (int ni = 0; ni < 4; ++ni)
      bfr[ni] = *(const s16x8*)&sB[(wc * 64 + ni * 16 + lr) * BKK + kg * 8];
#pragma unroll
    for (int mi = 0; mi < 4; ++mi)
#pragma unroll
      for (int ni = 0; ni < 4; ++ni)
        acc[mi][ni] = __builtin_amdgcn_mfma_f32_16x16x32_bf16(af[mi], bfr[ni], acc[mi][ni], 0, 0, 0);
  }
  const int r0 = bm * BM + wr * 64;
  const int c0 = bn * BN + wc * 64;
#pragma unroll
  for (int mi = 0; mi < 4; ++mi)
#pragma unroll
    for (int ni = 0; ni < 4; ++ni) {
      const int col = c0 + ni * 16 + lr;
      const float bv = bias[col];
#pragma unroll
      for (int e = 0; e < 4; ++e) {
        const int row = r0 + mi * 16 + kg * 4 + e;
        const float v = acc[mi][ni][e] + bv;
        if (C_BF16) ((unsigned short*)Cv)[(size_t)row * N + col] = f2bf(v);
        else        ((float*)Cv)[(size_t)row * N + col] = v;
      }
    }
}

// ---------------------------------------------------------------- encoder LSTM scan
__global__ __launch_bounds__(512) void lstm_scan(const float* __restrict__ pre,
    const float* __restrict__ Whh, unsigned short* __restrict__ hs, int T) {
  __shared__ unsigned short hb[2][2048];
  const int tid = threadIdx.x;
  const int l = tid & 63, w = tid >> 6;
  const int wg = blockIdx.x;
  const int lr = l & 15, kg = l >> 4;
  const int col = w * 16 + lr;
  const int rbase = kg * 4;

  s16x8 wf[4][4];
#pragma unroll
  for (int gi = 0; gi < 4; ++gi)
#pragma unroll
    for (int kk = 0; kk < 4; ++kk) {
      const float* p = Whh + (size_t)(gi * 128 + col) * 128 + kk * 32 + kg * 8;
#pragma unroll
      for (int e = 0; e < 8; ++e) wf[gi][kk][e] = (short)f2bf(p[e]);
    }
  for (int i = tid; i < 4096; i += 512) ((unsigned short*)hb)[i] = 0;
  float c[4] = {0.f, 0.f, 0.f, 0.f};

  const float* pbase = pre + ((size_t)(wg * 16 + rbase)) * 512 + col;
  float pf[16];
#pragma unroll
  for (int gi = 0; gi < 4; ++gi)
#pragma unroll
    for (int e = 0; e < 4; ++e) pf[gi * 4 + e] = pbase[e * 512 + gi * 128];
  __syncthreads();

  for (int t = 0; t < T; ++t) {
    const unsigned short* hc = hb[t & 1];
    unsigned short* hn = hb[(t & 1) ^ 1];
    s16x8 a[4];
#pragma unroll
    for (int kk = 0; kk < 4; ++kk) {
      const int byt = lr * 256 + ((kk * 64 + kg * 16) ^ ((lr & 7) << 4));
      a[kk] = *(const s16x8*)((const char*)hc + byt);
    }
    f32x4 acc[4];
#pragma unroll
    for (int gi = 0; gi < 4; ++gi)
      acc[gi] = (f32x4){pf[gi * 4], pf[gi * 4 + 1], pf[gi * 4 + 2], pf[gi * 4 + 3]};
    float pfn[16];
    if (t + 1 < T) {
      const float* pb2 = pbase + (size_t)(t + 1) * 65536;
#pragma unroll
      for (int gi = 0; gi < 4; ++gi)
#pragma unroll
        for (int e = 0; e < 4; ++e) pfn[gi * 4 + e] = pb2[e * 512 + gi * 128];
    } else {
#pragma unroll
      for (int i2 = 0; i2 < 16; ++i2) pfn[i2] = 0.f;
    }
#pragma unroll
    for (int kk = 0; kk < 4; ++kk)
#pragma unroll
      for (int gi = 0; gi < 4; ++gi)
        acc[gi] = __builtin_amdgcn_mfma_f32_16x16x32_bf16(a[kk], wf[gi][kk], acc[gi], 0, 0, 0);
#pragma unroll
    for (int e = 0; e < 4; ++e) {
      float gi_ = sigf(acc[0][e]);
      float gf  = sigf(acc[1][e]);
      float gg  = tanhf_(acc[2][e]);
      float go  = sigf(acc[3][e]);
      c[e] = gf * c[e] + gi_ * gg;
      float h = go * tanhf_(c[e]);
      unsigned short hu = f2bf(h);
      int row = rbase + e;
      int byt = row * 256 + ((col * 2) ^ ((row & 7) << 4));
      *(unsigned short*)((char*)hn + byt) = hu;
      hs[((size_t)t * 128 + wg * 16 + row) * 128 + col] = hu;
    }
#pragma unroll
    for (int i2 = 0; i2 < 16; ++i2) pf[i2] = pfn[i2];
    __syncthreads();
  }
}

// ---------------------------------------------------------------- self-contained decoder v4
// 128 WGs, one per batch, zero cross-WG sync, NO large per-thread arrays
// (R8-R11 lesson: they scratch-spill at any launch-bounds setting).
// K in LDS (skew-16). Weights + V streamed from L2 as uint4 (16B/lane,
// 4x fewer load issues than R7). Gate-interleaved fused LSTM nonlinearity
// (4-lane shfl). No softmax max-sub (|s|<1 by weight scale; validated R8-R11).
// h0/h1 ping-pong buffers fix the R8-R11 same-phase read/write race.

#define DEC_SMEM 147456

__global__ void __launch_bounds__(512, 1) decoder_single(
    const unsigned short* __restrict__ kb, const uint4* __restrict__ vP4,
    const uint4* __restrict__ w0q4,  const uint4* __restrict__ wh0q4,
    const uint4* __restrict__ wi1q4, const uint4* __restrict__ wh1q4,
    const uint4* __restrict__ wq4,   const uint4* __restrict__ wo4,
    const float* __restrict__ b0, const float* __restrict__ b1,
    const float* __restrict__ bq, const float* __restrict__ bo,
    const float* __restrict__ linW, const float* __restrict__ linb,
    float* __restrict__ out)
{
  extern __shared__ char smem[];
  unsigned short* Kl = (unsigned short*)smem;      // [512 rows][16 slots x 16B] skewed
  float* xin = (float*)(smem + 131072);            // [136] (y[4], ct[128], pad0[4])
  float* h0p = (float*)(smem + 131648);            // [2][128] ping-pong
  float* h1p = (float*)(smem + 132672);            // [2][128] ping-pong
  float* qx  = (float*)(smem + 133696);            // [128] (pre-scaled q)
  float* ctv = (float*)(smem + 134208);            // [128]
  float* sc  = (float*)(smem + 134720);            // [4][512] exp-scores
  float* avp = (float*)(smem + 142912);            // [4][128]
  float* part= (float*)(smem + 144960);            // [4][128]
  float* red = (float*)(smem + 147008);            // [32]
  float* isl = (float*)(smem + 147136);            // [4]

  const int b = blockIdx.x;
  const int tid = threadIdx.x;
  const int l = tid & 63, wv = tid >> 6;
  const int lb = l & ~3;                 // 4-lane group base (within wave)
  const int gate = tid & 3, o512 = tid >> 2;
  const int o128 = tid & 127, qd = tid >> 7;

  // ---- one-time K staging (coalesced read, skewed write slot'=(slot+t)&15)
  {
    const unsigned* kb32 = (const unsigned*)kb;
#pragma unroll
    for (int it = 0; it < 64; ++it) {
      const int i = tid + it * 512;                // i = t*64 + c32
      const int t = i >> 6, c32 = i & 63;
      const unsigned v = kb32[(size_t)t * 8192 + b * 64 + c32];
      const int slot = c32 >> 2, w32 = c32 & 3;
      *(unsigned*)((char*)Kl + t * 256 + (((slot + t) & 15) << 4) + w32 * 4) = v;
    }
  }
  const float b0r = b0[gate * 128 + o512];
  const float b1r = b1[gate * 128 + o512];
  const float bqr = bq[o128];
  const float bor = bo[o128];
  float cc0 = 0.f, cc1 = 0.f;

  if (tid < 136) xin[tid] = 0.f;
  if (tid < 128) { h0p[tid] = 0.f; h0p[128 + tid] = 0.f; h1p[tid] = 0.f; h1p[128 + tid] = 0.f; }
  __syncthreads();

  const float scale = 0.1767766952966369f;  // 1/sqrt(32)

  for (int s = 0; s < 64; ++s) {
    const float* h0c = h0p + (s & 1) * 128;        // read buffers
    float* h0n = h0p + ((s & 1) ^ 1) * 128;        // write buffers
    const float* h1c = h1p + (s & 1) * 128;
    float* h1n = h1p + ((s & 1) ^ 1) * 128;

    // ======== layer 0: W0 (17 uint4) + Wh0 (16 uint4) streamed
    {
      float a0 = b0r, a1 = 0.f, a2 = 0.f, a3 = 0.f;
      const uint4* wp = w0q4 + tid;
#pragma unroll
      for (int m = 0; m < 17; ++m) {
        const uint4 w = wp[m * 512];
        const f32x4 xA = *(const f32x4*)(xin + 8 * m);
        const f32x4 xB = *(const f32x4*)(xin + 8 * m + 4);
        a0 += xA[0] * bflo(w.x); a1 += xA[1] * bfhi(w.x);
        a2 += xA[2] * bflo(w.y); a3 += xA[3] * bfhi(w.y);
        a0 += xB[0] * bflo(w.z); a1 += xB[1] * bfhi(w.z);
        a2 += xB[2] * bflo(w.w); a3 += xB[3] * bfhi(w.w);
      }
      const uint4* hp = wh0q4 + tid;
#pragma unroll
      for (int m = 0; m < 16; ++m) {
        const uint4 w = hp[m * 512];
        const f32x4 hA = *(const f32x4*)(h0c + 8 * m);
        const f32x4 hB = *(const f32x4*)(h0c + 8 * m + 4);
        a0 += hA[0] * bflo(w.x); a1 += hA[1] * bfhi(w.x);
        a2 += hA[2] * bflo(w.y); a3 += hA[3] * bfhi(w.y);
        a0 += hB[0] * bflo(w.z); a1 += hB[1] * bfhi(w.z);
        a2 += hB[2] * bflo(w.w); a3 += hB[3] * bfhi(w.w);
      }
      const float gval = (a0 + a1) + (a2 + a3);
      const float iv = __shfl(gval, lb + 0);
      const float fv = __shfl(gval, lb + 1);
      const float gv = __shfl(gval, lb + 2);
      const float ov = __shfl(gval, lb + 3);
      cc0 = sigf(fv) * cc0 + sigf(iv) * tanhf_(gv);
      const float h = sigf(ov) * tanhf_(cc0);
      if (gate == 0) h0n[o512] = h;    // write buffer != read buffer: no race
    }
    __syncthreads();
    // ======== layer 1: Wi1 + Wh1 streamed (reads h0n, h1c; writes h1n)
    {
      float a0 = b1r, a1 = 0.f, a2 = 0.f, a3 = 0.f;
      const uint4* ip = wi1q4 + tid;
      const uint4* hp = wh1q4 + tid;
#pragma unroll
      for (int m = 0; m < 16; ++m) {
        const uint4 wi = ip[m * 512];
        const uint4 wh = hp[m * 512];
        const f32x4 aA = *(const f32x4*)(h0n + 8 * m);
        const f32x4 aB = *(const f32x4*)(h0n + 8 * m + 4);
        const f32x4 bA = *(const f32x4*)(h1c + 8 * m);
        const f32x4 bB = *(const f32x4*)(h1c + 8 * m + 4);
        a0 += aA[0] * bflo(wi.x) + bA[0] * bflo(wh.x);
        a1 += aA[1] * bfhi(wi.x) + bA[1] * bfhi(wh.x);
        a2 += aA[2] * bflo(wi.y) + bA[2] * bflo(wh.y);
        a3 += aA[3] * bfhi(wi.y) + bA[3] * bfhi(wh.y);
        a0 += aB[0] * bflo(wi.z) + bB[0] * bflo(wh.z);
        a1 += aB[1] * bfhi(wi.z) + bB[1] * bfhi(wh.z);
        a2 += aB[2] * bflo(wi.w) + bB[2] * bflo(wh.w);
        a3 += aB[3] * bfhi(wi.w) + bB[3] * bfhi(wh.w);
      }
      const float gval = (a0 + a1) + (a2 + a3);
      const float iv = __shfl(gval, lb + 0);
      const float fv = __shfl(gval, lb + 1);
      const float gv = __shfl(gval, lb + 2);
      const float ov = __shfl(gval, lb + 3);
      cc1 = sigf(fv) * cc1 + sigf(iv) * tanhf_(gv);
      const float h = sigf(ov) * tanhf_(cc1);
      if (gate == 0) h1n[o512] = h;
    }
    __syncthreads();
    // ======== q partials: Wq streamed (4 uint4), quarter K-split
    {
      float a0 = 0.f, a1 = 0.f, a2 = 0.f, a3 = 0.f;
#pragma unroll
      for (int m = 0; m < 4; ++m) {
        const uint4 w = wq4[(size_t)(qd * 4 + m) * 128 + o128];
        const f32x4 hA = *(const f32x4*)(h1n + qd * 32 + 8 * m);
        const f32x4 hB = *(const f32x4*)(h1n + qd * 32 + 8 * m + 4);
        a0 += hA[0] * bflo(w.x); a1 += hA[1] * bfhi(w.x);
        a2 += hA[2] * bflo(w.y); a3 += hA[3] * bfhi(w.y);
        a0 += hB[0] * bflo(w.z); a1 += hB[1] * bfhi(w.z);
        a2 += hB[2] * bflo(w.w); a3 += hB[3] * bfhi(w.w);
      }
      part[qd * 128 + o128] = (a0 + a1) + (a2 + a3);
    }
    __syncthreads();
    if (tid < 128)
      qx[tid] = (bqr + part[tid] + part[128 + tid] + part[256 + tid] + part[384 + tid]) * scale;
    __syncthreads();
    // ======== scores (exp, no max-sub) + wave sums
    {
      const int t = tid;
      float s0 = 0.f, s1 = 0.f, s2 = 0.f, s3 = 0.f;
      const char* krow = (const char*)Kl + t * 256;
#pragma unroll
      for (int c = 0; c < 16; ++c) {
        const s16x8 kv = *(const s16x8*)(krow + (((c + t) & 15) << 4));
        const f32x4 qA = *(const f32x4*)(qx + c * 8);
        const f32x4 qB = *(const f32x4*)(qx + c * 8 + 4);
        float d = qA[0] * bf2f(kv[0]) + qA[1] * bf2f(kv[1]) + qA[2] * bf2f(kv[2]) + qA[3] * bf2f(kv[3])
                + qB[0] * bf2f(kv[4]) + qB[1] * bf2f(kv[5]) + qB[2] * bf2f(kv[6]) + qB[3] * bf2f(kv[7]);
        if ((c >> 2) == 0) s0 += d; else if ((c >> 2) == 1) s1 += d; else if ((c >> 2) == 2) s2 += d; else s3 += d;
      }
      float p0 = __expf(s0), p1 = __expf(s1), p2 = __expf(s2), p3 = __expf(s3);
      sc[0 * 512 + t] = p0; sc[1 * 512 + t] = p1; sc[2 * 512 + t] = p2; sc[3 * 512 + t] = p3;
#pragma unroll
      for (int off = 32; off > 0; off >>= 1) {
        p0 += __shfl_xor(p0, off); p1 += __shfl_xor(p1, off);
        p2 += __shfl_xor(p2, off); p3 += __shfl_xor(p3, off);
      }
      if (l == 0) { red[0 + wv] = p0; red[8 + wv] = p1; red[16 + wv] = p2; red[24 + wv] = p3; }
    }
    __syncthreads();
    // ======== AV partials: V streamed as 16 uint4 (batch-contiguous, L2-hot)
    if (tid < 4) {
      float sm = red[tid * 8];
#pragma unroll
      for (int w2 = 1; w2 < 8; ++w2) sm += red[tid * 8 + w2];
      isl[tid] = 1.f / sm;
    }
    {
      const int h = o128 >> 5;
      const float* scp = sc + h * 512 + qd * 128;
      const uint4* vp = vP4 + (size_t)(b * 64 + qd * 16) * 128 + o128;
      float e0 = 0.f, e1 = 0.f, e2 = 0.f, e3 = 0.f;
#pragma unroll
      for (int m = 0; m < 16; ++m) {
        const uint4 v = vp[(size_t)m * 128];
        const f32x4 sA = *(const f32x4*)(scp + 8 * m);
        const f32x4 sB = *(const f32x4*)(scp + 8 * m + 4);
        e0 += sA[0] * bflo(v.x); e1 += sA[1] * bfhi(v.x);
        e2 += sA[2] * bflo(v.y); e3 += sA[3] * bfhi(v.y);
        e0 += sB[0] * bflo(v.z); e1 += sB[1] * bfhi(v.z);
        e2 += sB[2] * bflo(v.w); e3 += sB[3] * bfhi(v.w);
      }
      avp[qd * 128 + o128] = (e0 + e1) + (e2 + e3);
    }
    __syncthreads();
    if (tid < 128)
      ctv[tid] = (avp[tid] + avp[128 + tid] + avp[256 + tid] + avp[384 + tid]) * isl[tid >> 5];
    __syncthreads();
    // ======== ct partials: Wo streamed (4 uint4)
    {
      float a0 = 0.f, a1 = 0.f, a2 = 0.f, a3 = 0.f;
#pragma unroll
      for (int m = 0; m < 4; ++m) {
        const uint4 w = wo4[(size_t)(qd * 4 + m) * 128 + o128];
        const f32x4 cA = *(const f32x4*)(ctv + qd * 32 + 8 * m);
        const f32x4 cB = *(const f32x4*)(ctv + qd * 32 + 8 * m + 4);
        a0 += cA[0] * bflo(w.x); a1 += cA[1] * bfhi(w.x);
        a2 += cA[2] * bflo(w.y); a3 += cA[3] * bfhi(w.y);
        a0 += cB[0] * bflo(w.z); a1 += cB[1] * bfhi(w.z);
        a2 += cB[2] * bflo(w.w); a3 += cB[3] * bfhi(w.w);
      }
      part[qd * 128 + o128] = (a0 + a1) + (a2 + a3);
    }
    __syncthreads();
    if (tid < 128)
      xin[4 + tid] = bor + part[tid] + part[128 + tid] + part[256 + tid] + part[384 + tid];
    __syncthreads();
    // ======== y = [h1, ct] @ lin_W.T + lin_b
    if (tid < 256) {
      const int o = tid >> 6, j = tid & 63;
      const float* lw = linW + o * 256;
      float p = h1n[j] * lw[j] + h1n[j + 64] * lw[j + 64]
              + xin[4 + j] * lw[128 + j] + xin[4 + j + 64] * lw[192 + j];
#pragma unroll
      for (int off = 32; off > 0; off >>= 1) p += __shfl_xor(p, off);
      if (j == 0) {
        const float yv = p + linb[o];
        out[((size_t)s * 128 + b) * 4 + o] = yv;
        xin[o] = yv;
      }
    }
    __syncthreads();
  }
}

// ---------------------------------------------------------------- launch
extern "C" void kernel_launch(void* const* d_in, const int* in_sizes, int n_in,
                              void* d_out, int out_size, void* d_ws, size_t ws_size,
                              hipStream_t stream) {
  (void)in_sizes; (void)n_in; (void)out_size;
  const float* x     = (const float*)d_in[0];
  const float* eWih0 = (const float*)d_in[1];
  const float* eWhh0 = (const float*)d_in[2];
  const float* eb0   = (const float*)d_in[3];
  const float* eWih1 = (const float*)d_in[4];
  const float* eWhh1 = (const float*)d_in[5];
  const float* eb1   = (const float*)d_in[6];
  const float* dWih0 = (const float*)d_in[7];
  const float* dWhh0 = (const float*)d_in[8];
  const float* db0   = (const float*)d_in[9];
  const float* dWih1 = (const float*)d_in[10];
  const float* dWhh1 = (const float*)d_in[11];
  const float* db1   = (const float*)d_in[12];
  const float* Wq    = (const float*)d_in[13];
  const float* bq    = (const float*)d_in[14];
  const float* Wk    = (const float*)d_in[15];
  const float* bk    = (const float*)d_in[16];
  const float* Wv    = (const float*)d_in[17];
  const float* bv    = (const float*)d_in[18];
  const float* Wo    = (const float*)d_in[19];
  const float* bo    = (const float*)d_in[20];
  const float* linW  = (const float*)d_in[21];
  const float* linb  = (const float*)d_in[22];

  char* w = (char*)d_ws;
  float* pre  = (float*)(w + 524288);                    // 128 MB
  size_t off = 524288 + (size_t)65536 * 512 * 4;
  unsigned short* hs0  = (unsigned short*)(w + off); off += (size_t)65536 * 128 * 2;
  unsigned short* enc  = (unsigned short*)(w + off); off += (size_t)65536 * 128 * 2;
  unsigned short* kbuf = (unsigned short*)(w + off); off += (size_t)65536 * 128 * 2;
  unsigned short* vbuf = (unsigned short*)(w + off); off += (size_t)65536 * 128 * 2;
  uint4* w0q4  = (uint4*)(w + off); off += (size_t)17 * 512 * 16;
  uint4* wh0q4 = (uint4*)(w + off); off += (size_t)16 * 512 * 16;
  uint4* wi1q4 = (uint4*)(w + off); off += (size_t)16 * 512 * 16;
  uint4* wh1q4 = (uint4*)(w + off); off += (size_t)16 * 512 * 16;
  uint4* wq4   = (uint4*)(w + off); off += (size_t)16 * 128 * 16;
  uint4* wo4   = (uint4*)(w + off); off += (size_t)16 * 128 * 16;
  uint4* vP4   = (uint4*)(w + off); off += (size_t)128 * 64 * 128 * 16;   // 16 MB
  unsigned short* xbf = (unsigned short*)(w + off);
  const size_t need_big = off + (size_t)65536 * 1024 * 2;
  const bool big = ws_size >= need_big;

  // decoder weight packing (gate-interleaved uint4 for 512-wide matvecs)
  packTg4<<<(17 * 512 + 255) / 256, 256, 0, stream>>>(dWih0, w0q4, 132, 17);
  packTg4<<<(16 * 512 + 255) / 256, 256, 0, stream>>>(dWhh0, wh0q4, 128, 16);
  packTg4<<<(16 * 512 + 255) / 256, 256, 0, stream>>>(dWih1, wi1q4, 128, 16);
  packTg4<<<(16 * 512 + 255) / 256, 256, 0, stream>>>(dWhh1, wh1q4, 128, 16);
  packT4<<<(16 * 128 + 255) / 256, 256, 0, stream>>>(Wq, wq4);
  packT4<<<(16 * 128 + 255) / 256, 256, 0, stream>>>(Wo, wo4);

  // encoder
  if (big) {
    f2bf_vec<<<65536, 256, 0, stream>>>(x, xbf);        // one-shot f32->bf16
    gemm_bt<1, 0><<<dim3(4, 512), 256, 0, stream>>>((const void*)xbf, eWih0, eb0, (void*)pre, 65536, 512, 1024);
  } else {
    gemm_bt<0, 0><<<dim3(4, 512), 256, 0, stream>>>((const void*)x, eWih0, eb0, (void*)pre, 65536, 512, 1024);
  }
  lstm_scan<<<8, 512, 0, stream>>>(pre, eWhh0, hs0, 512);
  gemm_bt<1, 0><<<dim3(4, 512), 256, 0, stream>>>((const void*)hs0, eWih1, eb1, (void*)pre, 65536, 512, 128);
  lstm_scan<<<8, 512, 0, stream>>>(pre, eWhh1, enc, 512);
  // K/V projections
  gemm_bt<1, 1><<<dim3(1, 512), 256, 0, stream>>>((const void*)enc, Wk, bk, (void*)kbuf, 65536, 128, 128);
  gemm_bt<1, 1><<<dim3(1, 512), 256, 0, stream>>>((const void*)enc, Wv, bv, (void*)vbuf, 65536, 128, 128);
  vpack4<<<(128 * 64 * 128 + 255) / 256, 256, 0, stream>>>(vbuf, vP4);

  // self-contained decoder: 128 WGs, one per batch
  hipFuncSetAttribute((const void*)decoder_single,
                      hipFuncAttributeMaxDynamicSharedMemorySize, DEC_SMEM);
  decoder_single<<<128, 512, DEC_SMEM, stream>>>(kbuf, vP4, w0q4, wh0q4, wi1q4, wh1q4, wq4, wo4,
      db0, db1, bq, bo, linW, linb, (float*)d_out);
}

// Round 13
// 3645.049 us; speedup vs baseline: 2.2166x; 2.2166x over previous
//
#include <hip/hip_runtime.h>
#include <hip/hip_bf16.h>

typedef __attribute__((ext_vector_type(8))) short s16x8;
typedef __attribute__((ext_vector_type(4))) float f32x4;

__device__ inline unsigned short f2bf(float f) {
  unsigned u = __builtin_bit_cast(unsigned, f);
  unsigned r = (u + 0x7FFFu + ((u >> 16) & 1u)) >> 16;  // RTNE
  return (unsigned short)r;
}
__device__ inline float bf2f(short v) {
  return __builtin_bit_cast(float, ((unsigned)(unsigned short)v) << 16);
}
__device__ inline float bflo(unsigned w) { return __builtin_bit_cast(float, w << 16); }
__device__ inline float bfhi(unsigned w) { return __builtin_bit_cast(float, w & 0xFFFF0000u); }
__device__ inline float sigf(float x) { return 1.f / (1.f + __expf(-x)); }
__device__ inline float tanhf_(float x) { float e = __expf(2.f * x); return 1.f - 2.f / (e + 1.f); }

// ---------------------------------------------------------------- packers (u32 pairs, R7-proven address streams)
// standard: dst[kk*rows + o] = pack(bf16(src[o][2kk]), bf16(src[o][2kk+1]))
__global__ void packT(const float* __restrict__ src, unsigned* __restrict__ dst,
                      int rows, int scols, int kkPairs) {
  int i = blockIdx.x * 256 + threadIdx.x;
  if (i >= kkPairs * rows) return;
  int kk = i / rows, o = i % rows;
  int k0 = 2 * kk, k1 = 2 * kk + 1;
  float lo = (k0 < scols) ? src[(size_t)o * scols + k0] : 0.f;
  float hi = (k1 < scols) ? src[(size_t)o * scols + k1] : 0.f;
  dst[i] = (unsigned)f2bf(lo) | ((unsigned)f2bf(hi) << 16);
}
// gate-interleaved (rows==512): slot j covers src row (j&3)*128 + (j>>2).
// Same dst index space as packT -> IDENTICAL address stream on the read side.
__global__ void packTg(const float* __restrict__ src, unsigned* __restrict__ dst,
                       int scols, int kkPairs) {
  int i = blockIdx.x * 256 + threadIdx.x;
  if (i >= kkPairs * 512) return;
  int kk = i / 512, j = i % 512;
  int row = (j & 3) * 128 + (j >> 2);
  int k0 = 2 * kk, k1 = 2 * kk + 1;
  float lo = (k0 < scols) ? src[(size_t)row * scols + k0] : 0.f;
  float hi = (k1 < scols) ? src[(size_t)row * scols + k1] : 0.f;
  dst[i] = (unsigned)f2bf(lo) | ((unsigned)f2bf(hi) << 16);
}
// bulk f32 -> bf16
__global__ void f2bf_vec(const float* __restrict__ src, unsigned short* __restrict__ dst) {
  size_t i = ((size_t)blockIdx.x * 256 + threadIdx.x) * 4;
  float4 v = *(const float4*)(src + i);
  ushort4 o;
  o.x = f2bf(v.x); o.y = f2bf(v.y); o.z = f2bf(v.z); o.w = f2bf(v.w);
  *(ushort4*)(dst + i) = o;
}

// ---------------------------------------------------------------- GEMM C = A @ B^T + bias
#define BM 128
#define BN 128
#define BKK 32

template<int A_BF16, int C_BF16>
__global__ __launch_bounds__(256) void gemm_bt(const void* __restrict__ Av,
    const float* __restrict__ B, const float* __restrict__ bias,
    void* __restrict__ Cv, int M, int N, int K) {
  __shared__ short sA[BM * BKK];
  __shared__ short sB[BN * BKK];
  const int tid = threadIdx.x;
  const int l = tid & 63;
  const int wid = tid >> 6;
  const int wr = wid >> 1, wc = wid & 1;
  const int lr = l & 15, kg = l >> 4;
  const int bn = blockIdx.x, bm = blockIdx.y;
  const int arow = tid >> 1;
  const int acol = (tid & 1) * 16;

  f32x4 acc[4][4];
#pragma unroll
  for (int i = 0; i < 4; ++i)
#pragma unroll
    for (int j = 0; j < 4; ++j) acc[i][j] = (f32x4){0.f, 0.f, 0.f, 0.f};

  for (int kt = 0; kt < K; kt += BKK) {
    __syncthreads();
    if (A_BF16) {
      const unsigned short* src = (const unsigned short*)Av + (size_t)(bm * BM + arow) * K + kt + acol;
      *(s16x8*)&sA[arow * BKK + acol] = *(const s16x8*)src;
      *(s16x8*)&sA[arow * BKK + acol + 8] = *(const s16x8*)(src + 8);
    } else {
      const float* src = (const float*)Av + (size_t)(bm * BM + arow) * K + kt + acol;
      s16x8 v0, v1;
#pragma unroll
      for (int e = 0; e < 8; ++e) { v0[e] = (short)f2bf(src[e]); v1[e] = (short)f2bf(src[8 + e]); }
      *(s16x8*)&sA[arow * BKK + acol] = v0;
      *(s16x8*)&sA[arow * BKK + acol + 8] = v1;
    }
    {
      const float* src = B + (size_t)(bn * BN + arow) * K + kt + acol;
      s16x8 v0, v1;
#pragma unroll
      for (int e = 0; e < 8; ++e) { v0[e] = (short)f2bf(src[e]); v1[e] = (short)f2bf(src[8 + e]); }
      *(s16x8*)&sB[arow * BKK + acol] = v0;
      *(s16x8*)&sB[arow * BKK + acol + 8] = v1;
    }
    __syncthreads();
    s16x8 af[4], bfr[4];
#pragma unroll
    for (int mi = 0; mi < 4; ++mi)
      af[mi] = *(const s16x8*)&sA[(wr * 64 + mi * 16 + lr) * BKK + kg * 8];
#pragma unroll
    for (int ni = 0; ni < 4; ++ni)
      bfr[ni] = *(const s16x8*)&sB[(wc * 64 + ni * 16 + lr) * BKK + kg * 8];
#pragma unroll
    for (int mi = 0; mi < 4; ++mi)
#pragma unroll
      for (int ni = 0; ni < 4; ++ni)
        acc[mi][ni] = __builtin_amdgcn_mfma_f32_16x16x32_bf16(af[mi], bfr[ni], acc[mi][ni], 0, 0, 0);
  }
  const int r0 = bm * BM + wr * 64;
  const int c0 = bn * BN + wc * 64;
#pragma unroll
  for (int mi = 0; mi < 4; ++mi)
#pragma unroll
    for (int ni = 0; ni < 4; ++ni) {
      const int col = c0 + ni * 16 + lr;
      const float bv = bias[col];
#pragma unroll
      for (int e = 0; e < 4; ++e) {
        const int row = r0 + mi * 16 + kg * 4 + e;
        const float v = acc[mi][ni][e] + bv;
        if (C_BF16) ((unsigned short*)Cv)[(size_t)row * N + col] = f2bf(v);
        else        ((float*)Cv)[(size_t)row * N + col] = v;
      }
    }
}

// ---------------------------------------------------------------- encoder LSTM scan
__global__ __launch_bounds__(512) void lstm_scan(const float* __restrict__ pre,
    const float* __restrict__ Whh, unsigned short* __restrict__ hs, int T) {
  __shared__ unsigned short hb[2][2048];
  const int tid = threadIdx.x;
  const int l = tid & 63, w = tid >> 6;
  const int wg = blockIdx.x;
  const int lr = l & 15, kg = l >> 4;
  const int col = w * 16 + lr;
  const int rbase = kg * 4;

  s16x8 wf[4][4];
#pragma unroll
  for (int gi = 0; gi < 4; ++gi)
#pragma unroll
    for (int kk = 0; kk < 4; ++kk) {
      const float* p = Whh + (size_t)(gi * 128 + col) * 128 + kk * 32 + kg * 8;
#pragma unroll
      for (int e = 0; e < 8; ++e) wf[gi][kk][e] = (short)f2bf(p[e]);
    }
  for (int i = tid; i < 4096; i += 512) ((unsigned short*)hb)[i] = 0;
  float c[4] = {0.f, 0.f, 0.f, 0.f};

  const float* pbase = pre + ((size_t)(wg * 16 + rbase)) * 512 + col;
  float pf[16];
#pragma unroll
  for (int gi = 0; gi < 4; ++gi)
#pragma unroll
    for (int e = 0; e < 4; ++e) pf[gi * 4 + e] = pbase[e * 512 + gi * 128];
  __syncthreads();

  for (int t = 0; t < T; ++t) {
    const unsigned short* hc = hb[t & 1];
    unsigned short* hn = hb[(t & 1) ^ 1];
    s16x8 a[4];
#pragma unroll
    for (int kk = 0; kk < 4; ++kk) {
      const int byt = lr * 256 + ((kk * 64 + kg * 16) ^ ((lr & 7) << 4));
      a[kk] = *(const s16x8*)((const char*)hc + byt);
    }
    f32x4 acc[4];
#pragma unroll
    for (int gi = 0; gi < 4; ++gi)
      acc[gi] = (f32x4){pf[gi * 4], pf[gi * 4 + 1], pf[gi * 4 + 2], pf[gi * 4 + 3]};
    float pfn[16];
    if (t + 1 < T) {
      const float* pb2 = pbase + (size_t)(t + 1) * 65536;
#pragma unroll
      for (int gi = 0; gi < 4; ++gi)
#pragma unroll
        for (int e = 0; e < 4; ++e) pfn[gi * 4 + e] = pb2[e * 512 + gi * 128];
    } else {
#pragma unroll
      for (int i2 = 0; i2 < 16; ++i2) pfn[i2] = 0.f;
    }
#pragma unroll
    for (int kk = 0; kk < 4; ++kk)
#pragma unroll
      for (int gi = 0; gi < 4; ++gi)
        acc[gi] = __builtin_amdgcn_mfma_f32_16x16x32_bf16(a[kk], wf[gi][kk], acc[gi], 0, 0, 0);
#pragma unroll
    for (int e = 0; e < 4; ++e) {
      float gi_ = sigf(acc[0][e]);
      float gf  = sigf(acc[1][e]);
      float gg  = tanhf_(acc[2][e]);
      float go  = sigf(acc[3][e]);
      c[e] = gf * c[e] + gi_ * gg;
      float h = go * tanhf_(c[e]);
      unsigned short hu = f2bf(h);
      int row = rbase + e;
      int byt = row * 256 + ((col * 2) ^ ((row & 7) << 4));
      *(unsigned short*)((char*)hn + byt) = hu;
      hs[((size_t)t * 128 + wg * 16 + row) * 128 + col] = hu;
    }
#pragma unroll
    for (int i2 = 0; i2 < 16; ++i2) pf[i2] = pfn[i2];
    __syncthreads();
  }
}

// ---------------------------------------------------------------- self-contained decoder v5
// = R7's proven kernel (21 MB FETCH, fully L2-resident streams; all address
// patterns byte-identical) + pattern-preserving compute wins:
//   * gate-interleaved weight SEMANTICS (packTg) -> LSTM nonlinearity fused
//     into the gate phase via 4-lane shfl (no gb round-trip, -2 barriers/layer)
//   * no softmax max-subtraction (validated R8-R12), -2 barriers
//   * h0/h1 ping-pong (fixes same-phase read/write hazard)
// NO per-thread arrays (R8/R9 spill lesson), NO repacked V (R12 L2-alias lesson).

#define DEC_SMEM 147200

__global__ void __launch_bounds__(512, 1) decoder_single(
    const unsigned short* __restrict__ kb, const unsigned short* __restrict__ vb,
    const unsigned* __restrict__ w0t,  const unsigned* __restrict__ wh0t,
    const unsigned* __restrict__ wi1t, const unsigned* __restrict__ wh1t,
    const unsigned* __restrict__ wqt,  const unsigned* __restrict__ wot,
    const float* __restrict__ b0, const float* __restrict__ b1,
    const float* __restrict__ bq, const float* __restrict__ bo,
    const float* __restrict__ linW, const float* __restrict__ linb,
    float* __restrict__ out)
{
  extern __shared__ char smem[];
  unsigned short* Kl = (unsigned short*)smem;      // [512 rows][16 slots x 16B] skewed
  float* xin = (float*)(smem + 131072);            // [136] (y[4], ct[128], pad0)
  float* h0p = (float*)(smem + 131648);            // [2][128] ping-pong
  float* h1p = (float*)(smem + 132672);            // [2][128] ping-pong
  float* qx  = (float*)(smem + 133696);            // [128] (pre-scaled q)
  float* ctv = (float*)(smem + 134208);            // [128]
  float* sc  = (float*)(smem + 134720);            // [4][512] exp-scores
  float* avp = (float*)(smem + 142912);            // [4][128]
  float* part= (float*)(smem + 144960);            // [4][128]
  float* red = (float*)(smem + 147008);            // [32]
  float* isl = (float*)(smem + 147136);            // [4]

  const int b = blockIdx.x;
  const int tid = threadIdx.x;
  const int l = tid & 63, wv = tid >> 6;
  const int lb = l & ~3;                 // 4-lane group base (gates of one output)
  const int gate = tid & 3, o512 = tid >> 2;
  const int o128 = tid & 127, qd = tid >> 7;

  // ---- one-time K staging (coalesced read, skewed write slot'=(slot+t)&15) [R7-exact]
  {
    const unsigned* kb32 = (const unsigned*)kb;
#pragma unroll
    for (int it = 0; it < 64; ++it) {
      const int i = tid + it * 512;                // i = t*64 + c32
      const int t = i >> 6, c32 = i & 63;
      const unsigned v = kb32[(size_t)t * 8192 + b * 64 + c32];
      const int slot = c32 >> 2, w32 = c32 & 3;
      *(unsigned*)((char*)Kl + t * 256 + (((slot + t) & 15) << 4) + w32 * 4) = v;
    }
  }
  const float b0r = b0[gate * 128 + o512];
  const float b1r = b1[gate * 128 + o512];
  const float bqr = bq[o128];
  const float bor = bo[o128];
  float cc0 = 0.f, cc1 = 0.f;

  if (tid < 136) xin[tid] = 0.f;
  if (tid < 128) { h0p[tid] = 0.f; h0p[128 + tid] = 0.f; h1p[tid] = 0.f; h1p[128 + tid] = 0.f; }
  __syncthreads();

  const float scale = 0.1767766952966369f;  // 1/sqrt(32)

  for (int s = 0; s < 64; ++s) {
    const float* h0c = h0p + (s & 1) * 128;
    float* h0n = h0p + ((s & 1) ^ 1) * 128;
    const float* h1c = h1p + (s & 1) * 128;
    float* h1n = h1p + ((s & 1) ^ 1) * 128;

    // ======== layer 0: W0 (68 u32) + Wh0 (64 u32) streamed [R7 address pattern]
    {
      float a0 = b0r, a1 = 0.f;
      const unsigned* wp = w0t + tid;
#pragma unroll 8
      for (int kk = 0; kk < 68; ++kk) {
        const unsigned w2 = wp[kk * 512];
        const float2 x2 = *(const float2*)(xin + 2 * kk);
        a0 += x2.x * bflo(w2); a1 += x2.y * bfhi(w2);
      }
      const unsigned* hp = wh0t + tid;
#pragma unroll 8
      for (int kk = 0; kk < 64; ++kk) {
        const unsigned w2 = hp[kk * 512];
        const float2 h2 = *(const float2*)(h0c + 2 * kk);
        a0 += h2.x * bflo(w2); a1 += h2.y * bfhi(w2);
      }
      const float gval = a0 + a1;
      const float iv = __shfl(gval, lb + 0);
      const float fv = __shfl(gval, lb + 1);
      const float gv = __shfl(gval, lb + 2);
      const float ov = __shfl(gval, lb + 3);
      cc0 = sigf(fv) * cc0 + sigf(iv) * tanhf_(gv);
      const float h = sigf(ov) * tanhf_(cc0);
      if (gate == 0) h0n[o512] = h;     // write buf != read buf: race-free
    }
    __syncthreads();
    // ======== layer 1: Wi1 + Wh1 streamed (reads h0n, h1c; writes h1n)
    {
      float a0 = b1r, a1 = 0.f;
      const unsigned* ip = wi1t + tid;
      const unsigned* hp = wh1t + tid;
#pragma unroll 8
      for (int kk = 0; kk < 64; ++kk) {
        const unsigned wa = ip[kk * 512];
        const unsigned wb = hp[kk * 512];
        const float2 a2 = *(const float2*)(h0n + 2 * kk);
        const float2 b2 = *(const float2*)(h1c + 2 * kk);
        a0 += a2.x * bflo(wa) + b2.x * bflo(wb);
        a1 += a2.y * bfhi(wa) + b2.y * bfhi(wb);
      }
      const float gval = a0 + a1;
      const float iv = __shfl(gval, lb + 0);
      const float fv = __shfl(gval, lb + 1);
      const float gv = __shfl(gval, lb + 2);
      const float ov = __shfl(gval, lb + 3);
      cc1 = sigf(fv) * cc1 + sigf(iv) * tanhf_(gv);
      const float h = sigf(ov) * tanhf_(cc1);
      if (gate == 0) h1n[o512] = h;
    }
    __syncthreads();
    // ======== q partials: Wq streamed (16 u32, quarter K-split) [R7-exact]
    {
      float a0 = 0.f, a1 = 0.f;
      const unsigned* wp = wqt + (size_t)(qd * 16) * 128 + o128;
#pragma unroll
      for (int m = 0; m < 16; ++m) {
        const unsigned w2 = wp[(size_t)m * 128];
        const float2 h2 = *(const float2*)(h1n + qd * 32 + 2 * m);
        a0 += h2.x * bflo(w2);
        a1 += h2.y * bfhi(w2);
      }
      part[qd * 128 + o128] = a0 + a1;
    }
    __syncthreads();
    if (tid < 128)
      qx[tid] = (bqr + part[tid] + part[128 + tid] + part[256 + tid] + part[384 + tid]) * scale;
    __syncthreads();
    // ======== scores: exp (no max-sub) + wave sums [R12's validated fold]
    {
      const int t = tid;
      float s0 = 0.f, s1 = 0.f, s2 = 0.f, s3 = 0.f;
      const char* krow = (const char*)Kl + t * 256;
#pragma unroll
      for (int c = 0; c < 16; ++c) {
        const s16x8 kv = *(const s16x8*)(krow + (((c + t) & 15) << 4));
        const f32x4 qA = *(const f32x4*)(qx + c * 8);
        const f32x4 qB = *(const f32x4*)(qx + c * 8 + 4);
        float d = qA[0] * bf2f(kv[0]) + qA[1] * bf2f(kv[1]) + qA[2] * bf2f(kv[2]) + qA[3] * bf2f(kv[3])
                + qB[0] * bf2f(kv[4]) + qB[1] * bf2f(kv[5]) + qB[2] * bf2f(kv[6]) + qB[3] * bf2f(kv[7]);
        if ((c >> 2) == 0) s0 += d; else if ((c >> 2) == 1) s1 += d; else if ((c >> 2) == 2) s2 += d; else s3 += d;
      }
      float p0 = __expf(s0), p1 = __expf(s1), p2 = __expf(s2), p3 = __expf(s3);
      sc[0 * 512 + t] = p0; sc[1 * 512 + t] = p1; sc[2 * 512 + t] = p2; sc[3 * 512 + t] = p3;
#pragma unroll
      for (int off = 32; off > 0; off >>= 1) {
        p0 += __shfl_xor(p0, off); p1 += __shfl_xor(p1, off);
        p2 += __shfl_xor(p2, off); p3 += __shfl_xor(p3, off);
      }
      if (l == 0) { red[0 + wv] = p0; red[8 + wv] = p1; red[16 + wv] = p2; red[24 + wv] = p3; }
    }
    __syncthreads();
    // ======== AV partials: V streamed scalar from vbuf [R7-exact address pattern]
    if (tid < 4) {
      float sm = red[tid * 8];
#pragma unroll
      for (int w2 = 1; w2 < 8; ++w2) sm += red[tid * 8 + w2];
      isl[tid] = 1.f / sm;
    }
    {
      const int d = tid & 127, tc = tid >> 7, h = d >> 5;
      const unsigned short* vp = vb + (size_t)(tc * 128) * 16384 + (size_t)b * 128 + d;
      const float* scp = sc + h * 512 + tc * 128;
      float acc = 0.f;
#pragma unroll 8
      for (int tt = 0; tt < 128; ++tt)
        acc += scp[tt] * bf2f((short)vp[(size_t)tt * 16384]);
      avp[tc * 128 + d] = acc;
    }
    __syncthreads();
    if (tid < 128)
      ctv[tid] = (avp[tid] + avp[128 + tid] + avp[256 + tid] + avp[384 + tid]) * isl[tid >> 5];
    __syncthreads();
    // ======== ct partials: Wo streamed (16 u32) [R7-exact]
    {
      float a0 = 0.f, a1 = 0.f;
      const unsigned* wp = wot + (size_t)(qd * 16) * 128 + o128;
#pragma unroll
      for (int m = 0; m < 16; ++m) {
        const unsigned w2 = wp[(size_t)m * 128];
        const float2 c2 = *(const float2*)(ctv + qd * 32 + 2 * m);
        a0 += c2.x * bflo(w2);
        a1 += c2.y * bfhi(w2);
      }
      part[qd * 128 + o128] = a0 + a1;
    }
    __syncthreads();
    if (tid < 128)
      xin[4 + tid] = bor + part[tid] + part[128 + tid] + part[256 + tid] + part[384 + tid];
    __syncthreads();
    // ======== y = [h1, ct] @ lin_W.T + lin_b
    if (tid < 256) {
      const int o = tid >> 6, j = tid & 63;
      const float* lw = linW + o * 256;
      float p = h1n[j] * lw[j] + h1n[j + 64] * lw[j + 64]
              + xin[4 + j] * lw[128 + j] + xin[4 + j + 64] * lw[192 + j];
#pragma unroll
      for (int off = 32; off > 0; off >>= 1) p += __shfl_xor(p, off);
      if (j == 0) {
        const float yv = p + linb[o];
        out[((size_t)s * 128 + b) * 4 + o] = yv;
        xin[o] = yv;
      }
    }
    __syncthreads();
  }
}

// ---------------------------------------------------------------- launch
extern "C" void kernel_launch(void* const* d_in, const int* in_sizes, int n_in,
                              void* d_out, int out_size, void* d_ws, size_t ws_size,
                              hipStream_t stream) {
  (void)in_sizes; (void)n_in; (void)out_size;
  const float* x     = (const float*)d_in[0];
  const float* eWih0 = (const float*)d_in[1];
  const float* eWhh0 = (const float*)d_in[2];
  const float* eb0   = (const float*)d_in[3];
  const float* eWih1 = (const float*)d_in[4];
  const float* eWhh1 = (const float*)d_in[5];
  const float* eb1   = (const float*)d_in[6];
  const float* dWih0 = (const float*)d_in[7];
  const float* dWhh0 = (const float*)d_in[8];
  const float* db0   = (const float*)d_in[9];
  const float* dWih1 = (const float*)d_in[10];
  const float* dWhh1 = (const float*)d_in[11];
  const float* db1   = (const float*)d_in[12];
  const float* Wq    = (const float*)d_in[13];
  const float* bq    = (const float*)d_in[14];
  const float* Wk    = (const float*)d_in[15];
  const float* bk    = (const float*)d_in[16];
  const float* Wv    = (const float*)d_in[17];
  const float* bv    = (const float*)d_in[18];
  const float* Wo    = (const float*)d_in[19];
  const float* bo    = (const float*)d_in[20];
  const float* linW  = (const float*)d_in[21];
  const float* linb  = (const float*)d_in[22];

  char* w = (char*)d_ws;
  float* pre  = (float*)(w + 524288);                    // 128 MB
  size_t off = 524288 + (size_t)65536 * 512 * 4;
  unsigned short* hs0  = (unsigned short*)(w + off); off += (size_t)65536 * 128 * 2;
  unsigned short* enc  = (unsigned short*)(w + off); off += (size_t)65536 * 128 * 2;
  unsigned short* kbuf = (unsigned short*)(w + off); off += (size_t)65536 * 128 * 2;
  unsigned short* vbuf = (unsigned short*)(w + off); off += (size_t)65536 * 128 * 2;
  unsigned* w0t  = (unsigned*)(w + off); off += (size_t)68 * 512 * 4;
  unsigned* wh0t = (unsigned*)(w + off); off += (size_t)64 * 512 * 4;
  unsigned* wi1t = (unsigned*)(w + off); off += (size_t)64 * 512 * 4;
  unsigned* wh1t = (unsigned*)(w + off); off += (size_t)64 * 512 * 4;
  unsigned* wqt  = (unsigned*)(w + off); off += (size_t)64 * 128 * 4;
  unsigned* wot  = (unsigned*)(w + off); off += (size_t)64 * 128 * 4;
  unsigned short* xbf = (unsigned short*)(w + off);
  const size_t need_big = off + (size_t)65536 * 1024 * 2;
  const bool big = ws_size >= need_big;

  // decoder weight packing: gate-interleaved semantics, R7 address streams
  packTg<<<(68 * 512 + 255) / 256, 256, 0, stream>>>(dWih0, w0t, 132, 68);
  packTg<<<(64 * 512 + 255) / 256, 256, 0, stream>>>(dWhh0, wh0t, 128, 64);
  packTg<<<(64 * 512 + 255) / 256, 256, 0, stream>>>(dWih1, wi1t, 128, 64);
  packTg<<<(64 * 512 + 255) / 256, 256, 0, stream>>>(dWhh1, wh1t, 128, 64);
  packT<<<(64 * 128 + 255) / 256, 256, 0, stream>>>(Wq, wqt, 128, 128, 64);
  packT<<<(64 * 128 + 255) / 256, 256, 0, stream>>>(Wo, wot, 128, 128, 64);

  // encoder
  if (big) {
    f2bf_vec<<<65536, 256, 0, stream>>>(x, xbf);        // one-shot f32->bf16
    gemm_bt<1, 0><<<dim3(4, 512), 256, 0, stream>>>((const void*)xbf, eWih0, eb0, (void*)pre, 65536, 512, 1024);
  } else {
    gemm_bt<0, 0><<<dim3(4, 512), 256, 0, stream>>>((const void*)x, eWih0, eb0, (void*)pre, 65536, 512, 1024);
  }
  lstm_scan<<<8, 512, 0, stream>>>(pre, eWhh0, hs0, 512);
  gemm_bt<1, 0><<<dim3(4, 512), 256, 0, stream>>>((const void*)hs0, eWih1, eb1, (void*)pre, 65536, 512, 128);
  lstm_scan<<<8, 512, 0, stream>>>(pre, eWhh1, enc, 512);
  // K/V projections
  gemm_bt<1, 1><<<dim3(1, 512), 256, 0, stream>>>((const void*)enc, Wk, bk, (void*)kbuf, 65536, 128, 128);
  gemm_bt<1, 1><<<dim3(1, 512), 256, 0, stream>>>((const void*)enc, Wv, bv, (void*)vbuf, 65536, 128, 128);

  // self-contained decoder: 128 WGs, one per batch
  hipFuncSetAttribute((const void*)decoder_single,
                      hipFuncAttributeMaxDynamicSharedMemorySize, DEC_SMEM);
  decoder_single<<<128, 512, DEC_SMEM, stream>>>(kbuf, vbuf, w0t, wh0t, wi1t, wh1t, wqt, wot,
      db0, db1, bq, bo, linW, linb, (float*)d_out);
}